// Round 8
// baseline (20.062 us; speedup 1.0000x reference)
//
#include <hip/hip_runtime.h>
#include <math.h>

#define NCC  32
#define EPSF 1e-10f
#define TPB  512

// ---------------------------------------------------------------------------
// Compile-time reproduction of numpy's SVD null-space basis (validated R1/R4):
// np.linalg.svd -> dgesdd (m=31 < n=64, jobz='A', n >= MNTHR) -> Path 4t:
// Vt[31:, :] == Q[31:, :] from the Householder LQ (dgelqf) of L.
// A = B @ theta = Q^T [0_31; theta]. Double precision at compile time; cast
// to f32 per entry (matches reference's jnp.asarray(B_NP, float32)).
// ---------------------------------------------------------------------------
struct MTab { float mt[33][64]; };

constexpr double csqrt_(double x) {
    double y = x > 1.0 ? x : 1.0;
    for (int i = 0; i < 80; ++i) y = 0.5 * (y + x / y);
    return y;
}

constexpr MTab make_mtab() {
    double Lm[31][64] = {};
    for (int k = 1; k < 32; ++k) {
        double xk = (double)k / 32.0;
        Lm[k - 1][2 * (k - 1)]     = xk;
        Lm[k - 1][2 * (k - 1) + 1] = 1.0;
        Lm[k - 1][2 * k]           = -xk;
        Lm[k - 1][2 * k + 1]       = -1.0;
    }
    double tau[31] = {};
    for (int i = 0; i < 31; ++i) {
        int E = 2 * i + 3; if (E > 63) E = 63;
        double xn2 = 0.0;
        for (int p = i + 1; p <= E; ++p) xn2 += Lm[i][p] * Lm[i][p];
        const double alpha = Lm[i][i];
        double tu = 0.0, sc = 0.0;
        if (xn2 != 0.0) {
            const double nrm  = csqrt_(alpha * alpha + xn2);
            const double beta = (alpha >= 0.0) ? -nrm : nrm;   // dlarfg sign
            tu = (beta - alpha) / beta;
            sc = 1.0 / (alpha - beta);
        }
        for (int p = i + 1; p <= E; ++p) Lm[i][p] *= sc;
        Lm[i][i] = 1.0;
        tau[i] = tu;
        for (int j = i + 1; j < 31; ++j) {
            double s = 0.0;
            for (int p = i; p <= E; ++p) s += Lm[i][p] * Lm[j][p];
            s *= tu;
            for (int p = i; p <= E; ++p) Lm[j][p] -= s * Lm[i][p];
        }
    }
    MTab o{};
    for (int col = 0; col < 33; ++col) {
        double u[64] = {};
        u[31 + col] = 1.0;
        for (int i = 30; i >= 0; --i) {
            int E = 2 * i + 3; if (E > 63) E = 63;
            double s = 0.0;
            for (int p = i; p <= E; ++p) s += Lm[i][p] * u[p];
            s *= tau[i];
            for (int p = i; p <= E; ++p) u[p] -= s * Lm[i][p];
        }
        for (int p = 0; p < 64; ++p) o.mt[col][p] = (float)u[p];
    }
    return o;
}

__constant__ const MTab dM = make_mtab();

// ---------------------------------------------------------------------------
// Invariants (validated R5-R7, bit-level): after a crossing, xs is the exact
// boundary float c'*2^-5; direction never flips; t_hit / a*t_hit for steps
// >= 1 are per-(cell,dir) constants. NEW (R8): the sequential f32 chain
// t_k = fsub(t_{k-1}, th_k) is monotone in t0, so "crossing k happens" ==
// t0 > U_k where U_k = S_{k-1} + th_k (cumsum). With U'_k = prefix-max,
// crossing count m = #{k: t0 > U'_k} -> 6-step branchless binary search,
// NO divergent loop. Deviation from the reference's chain is bounded by
// 32 ulp (~2e-6) in t; decision flips confined to that band where the flow
// is continuous -> output deltas ~1e-6, invisible below the 0.0039 floor.
// Step-0 and terminal math remain byte-identical to the reference.
// ---------------------------------------------------------------------------
__global__ __launch_bounds__(TPB) void cpab_flow(const float* __restrict__ x_in,
                                                 const float* __restrict__ theta,
                                                 float* __restrict__ out, int n) {
    __shared__ float sA[64];
    __shared__ float aS[NCC], bS[NCC], boaS[NCC], vLS[NCC], vRS[NCC];
    __shared__ float thf[2][NCC], ljf[2][NCC];
    __shared__ float Up[2 * NCC][33];   // prefix-max of U_k, k=1..32
    __shared__ float Sa[2 * NCC][33];   // cumsum S_k, k=0..32
    __shared__ float La[2 * NCC][33];   // cumsum of fl32(a*th), k=0..32

    const int   tid = threadIdx.x;
    const float INF = __builtin_inff();

    if (tid < 64) {
        float acc = 0.0f;
#pragma unroll
        for (int j = 0; j < 33; ++j) acc = fmaf(dM.mt[j][tid], theta[j], acc);
        sA[tid] = acc;
    }
    __syncthreads();
    if (tid < NCC) {
        const float a   = sA[2 * tid];
        const float b   = sA[2 * tid + 1];
        const bool  big = fabsf(a) > EPSF;
        aS[tid]   = a;
        bS[tid]   = b;
        boaS[tid] = b / (big ? a : 1.0f);                       // IEEE divide
        vLS[tid]  = __fadd_rn(__fmul_rn(a, __fmul_rn((float)tid,       0.03125f)), b);
        vRS[tid]  = __fadd_rn(__fmul_rn(a, __fmul_rn((float)(tid + 1), 0.03125f)), b);
    }
    __syncthreads();
    if (tid < 2 * NCC) {
        // thf[d][c]: reference t_hit for cell c entered moving d (1=right,
        // entry=c*h; 0=left, entry=(c+1)*h). Byte-identical expressions.
        const int   c     = tid & 31;
        const int   dd    = tid >> 5;
        const float a     = aS[c];
        const float b     = bS[c];
        const float entry = __fmul_rn((float)(c + (dd ? 0 : 1)), 0.03125f);
        const float v     = dd ? vLS[c] : vRS[c];
        const bool  dirA  = v > 0.0f;
        const bool  fin   = dirA ? (c < NCC - 1) : (c > 0);
        const float xb    = __fmul_rn((float)(c + (dirA ? 1 : 0)), 0.03125f);
        const float xcs   = fin ? xb : entry;
        const float vc    = fin ? (dirA ? vRS[c] : vLS[c]) : v;
        const bool  v0    = (v == 0.0f);
        const float r     = vc / (v0 ? 1.0f : v);               // IEEE divide
        const bool  big   = fabsf(a) > EPSF;
        const float a_s   = big ? a : 1.0f;
        const float th_a  = logf(fmaxf(r, EPSF)) / a_s;         // libm + divide
        const float bb    = (fabsf(b) > EPSF) ? b : 1.0f;
        const float th_b  = __fsub_rn(xcs, entry) / bb;
        float t_hit = big ? ((r > EPSF) ? th_a : INF) : th_b;
        const bool valid = fin && !v0 && (t_hit > 0.0f);
        t_hit = valid ? t_hit : INF;
        thf[dd][c] = t_hit;
        ljf[dd][c] = __fmul_rn(a, t_hit);
    }
    __syncthreads();
    if (tid < 2 * NCC) {
        // Per-(start cell c1, dir) cumsum walk. Clamped entries (extreme
        // cell / OOB / th>2) get th=4 > 1 >= t0, so the search never selects
        // past them and their values never enter live state.
        const int d  = tid >> 5;
        const int c1 = tid & 31;
        const int dh = d ? 1 : -1;
        float S = 0.0f, LJ = 0.0f, Um = -INF;
        Sa[tid][0] = 0.0f;
        La[tid][0] = 0.0f;
        for (int k = 1; k <= 32; ++k) {
            const int cell = c1 + (k - 1) * dh;
            float th = 4.0f, lp = 0.0f;
            if (cell >= 0 && cell < NCC) {
                th = thf[d][cell];
                lp = ljf[d][cell];
                if (!(th <= 2.0f)) { th = 4.0f; lp = 0.0f; }
            }
            const float U = __fadd_rn(S, th);    // U_k == S_k (same chain)
            Um = fmaxf(Um, U);
            S  = U;
            LJ = __fadd_rn(LJ, lp);
            Up[tid][k] = Um;
            Sa[tid][k] = S;
            La[tid][k] = LJ;
        }
    }
    __syncthreads();

    const int ti   = blockIdx.x * blockDim.x + tid;
    const int base = ti << 2;
    if (base >= n) return;
    const bool full = (base + 3 < n);

    float4 xv;
    if (full) {
        xv = *reinterpret_cast<const float4*>(x_in + base);
    } else {
        xv.x = x_in[base];
        xv.y = (base + 1 < n) ? x_in[base + 1] : 0.0f;
        xv.z = (base + 2 < n) ? x_in[base + 2] : 0.0f;
        xv.w = 0.0f;
    }
    float4 zo, jo;

#pragma unroll
    for (int q = 0; q < 4; ++q) {
        const float x0 = (q == 0) ? xv.x : (q == 1) ? xv.y : (q == 2) ? xv.z : xv.w;
        int c0 = (int)floorf(__fmul_rn(x0, 32.0f));
        c0 = min(max(c0, 0), NCC - 1);

        // ---- step 0: full reference math from arbitrary x0 (byte-exact) ----
        const float a    = aS[c0];
        const float b    = bS[c0];
        const float v    = __fadd_rn(__fmul_rn(a, x0), b);
        const bool  dirA = v > 0.0f;
        const bool  fin  = dirA ? (c0 < NCC - 1) : (c0 > 0);
        const float xb   = __fmul_rn((float)(c0 + (dirA ? 1 : 0)), 0.03125f);
        const float xcs  = fin ? xb : x0;
        const float vc   = fin ? (dirA ? vRS[c0] : vLS[c0]) : v;
        const bool  v0   = (v == 0.0f);
        const float r    = vc / (v0 ? 1.0f : v);                // IEEE divide
        const bool  big  = fabsf(a) > EPSF;
        const float a_s  = big ? a : 1.0f;
        const float th_a = logf(fmaxf(r, EPSF)) / a_s;          // libm + divide
        float th_b = 0.0f;
        if (__any(!big)) {   // dead for gaussian A; exact when taken
            const float bb = (fabsf(b) > EPSF) ? b : 1.0f;
            th_b = __fsub_rn(xcs, x0) / bb;
        }
        float th = big ? ((r > EPSF) ? th_a : INF) : th_b;
        const bool valid = fin && !v0 && (th > 0.0f);
        th = valid ? th : INF;

        const bool  cross0 = th < 1.0f;
        const float t0     = __fsub_rn(1.0f, th);   // garbage if !cross0 (<=0)
        const float lj0    = __fmul_rn(a, th);
        const int   dh     = dirA ? 1 : -1;
        const int   c1     = c0 + dh;
        const int   c1c    = min(max(c1, 0), NCC - 1);
        const int   row    = (dirA ? NCC : 0) + c1c;

        // ---- crossing count: branchless binary search (wave-uniform) ----
        int m = 0;
#pragma unroll
        for (int s = 32; s >= 1; s >>= 1) {
            const int   cand  = m + s;
            const int   candc = min(cand, 32);
            const float u     = Up[row][candc];
            m = ((cand <= 32) && (t0 > u)) ? cand : m;
        }
        const float Sm = Sa[row][m];
        const float Lm = La[row][m];

        const float t  = cross0 ? __fsub_rn(t0, Sm) : 1.0f;   // m=0: == t0 exact
        const float lj = cross0 ? __fadd_rn(lj0, Lm) : 0.0f;  // m=0: == lj0
        int cf = cross0 ? (c1 + m * dh) : c0;
        cf = min(max(cf, 0), NCC - 1);
        const float xs = cross0 ? __fmul_rn((float)(cf + (dirA ? 0 : 1)), 0.03125f)
                                : x0;

        // ---- terminal step: dt = t, psi closed form (byte-exact) ----
        const float af   = aS[cf];
        const float bf   = bS[cf];
        const bool  bigf = fabsf(af) > EPSF;
        const float boa  = boaS[cf];
        const float ad   = __fmul_rn(af, t);
        const float ea   = expf(ad);                             // libm exp
        const float psi  = bigf ? __fsub_rn(__fmul_rn(ea, __fadd_rn(xs, boa)), boa)
                                : __fadd_rn(xs, __fmul_rn(bf, t));
        const float ljo  = __fadd_rn(lj, ad);
        if (q == 0) { zo.x = psi; jo.x = ljo; }
        if (q == 1) { zo.y = psi; jo.y = ljo; }
        if (q == 2) { zo.z = psi; jo.z = ljo; }
        if (q == 3) { zo.w = psi; jo.w = ljo; }
    }

    if (full) {
        *reinterpret_cast<float4*>(out + base)     = zo;
        *reinterpret_cast<float4*>(out + n + base) = jo;
    } else {
        out[base] = zo.x;             out[n + base] = jo.x;
        if (base + 1 < n) { out[base + 1] = zo.y; out[n + base + 1] = jo.y; }
        if (base + 2 < n) { out[base + 2] = zo.z; out[n + base + 2] = jo.z; }
    }
}

extern "C" void kernel_launch(void* const* d_in, const int* in_sizes, int n_in,
                              void* d_out, int out_size, void* d_ws, size_t ws_size,
                              hipStream_t stream) {
    (void)d_ws; (void)ws_size; (void)n_in; (void)out_size;
    const float* x     = (const float*)d_in[0];
    const float* theta = (const float*)d_in[1];
    float*       out   = (float*)d_out;
    const int    n     = in_sizes[0];

    const int threads4 = (n + 3) >> 2;
    const int blocks   = (threads4 + TPB - 1) / TPB;
    cpab_flow<<<blocks, TPB, 0, stream>>>(x, theta, out, n);
}

// Round 9
// 18.625 us; speedup vs baseline: 1.0772x; 1.0772x over previous
//
#include <hip/hip_runtime.h>
#include <math.h>

#define NCC  32
#define EPSF 1e-10f
#define TPB  512

// ---------------------------------------------------------------------------
// Compile-time reproduction of numpy's SVD null-space basis (validated R1/R4):
// np.linalg.svd -> dgesdd (m=31<n=64, jobz='A') -> Path 4t: Vt[31:,:] ==
// Q[31:,:] of the Householder LQ (dgelqf) of L. A = B@theta = Q^T [0;theta].
// ---------------------------------------------------------------------------
struct MTab { float mt[33][64]; };

constexpr double csqrt_(double x) {
    double y = x > 1.0 ? x : 1.0;
    for (int i = 0; i < 80; ++i) y = 0.5 * (y + x / y);
    return y;
}

constexpr MTab make_mtab() {
    double Lm[31][64] = {};
    for (int k = 1; k < 32; ++k) {
        double xk = (double)k / 32.0;
        Lm[k - 1][2 * (k - 1)]     = xk;
        Lm[k - 1][2 * (k - 1) + 1] = 1.0;
        Lm[k - 1][2 * k]           = -xk;
        Lm[k - 1][2 * k + 1]       = -1.0;
    }
    double tau[31] = {};
    for (int i = 0; i < 31; ++i) {
        int E = 2 * i + 3; if (E > 63) E = 63;
        double xn2 = 0.0;
        for (int p = i + 1; p <= E; ++p) xn2 += Lm[i][p] * Lm[i][p];
        const double alpha = Lm[i][i];
        double tu = 0.0, sc = 0.0;
        if (xn2 != 0.0) {
            const double nrm  = csqrt_(alpha * alpha + xn2);
            const double beta = (alpha >= 0.0) ? -nrm : nrm;   // dlarfg sign
            tu = (beta - alpha) / beta;
            sc = 1.0 / (alpha - beta);
        }
        for (int p = i + 1; p <= E; ++p) Lm[i][p] *= sc;
        Lm[i][i] = 1.0;
        tau[i] = tu;
        for (int j = i + 1; j < 31; ++j) {
            double s = 0.0;
            for (int p = i; p <= E; ++p) s += Lm[i][p] * Lm[j][p];
            s *= tu;
            for (int p = i; p <= E; ++p) Lm[j][p] -= s * Lm[i][p];
        }
    }
    MTab o{};
    for (int col = 0; col < 33; ++col) {
        double u[64] = {};
        u[31 + col] = 1.0;
        for (int i = 30; i >= 0; --i) {
            int E = 2 * i + 3; if (E > 63) E = 63;
            double s = 0.0;
            for (int p = i; p <= E; ++p) s += Lm[i][p] * u[p];
            s *= tau[i];
            for (int p = i; p <= E; ++p) u[p] -= s * Lm[i][p];
        }
        for (int p = 0; p < 64; ++p) o.mt[col][p] = (float)u[p];
    }
    return o;
}

__constant__ const MTab dM = make_mtab();

// ---------------------------------------------------------------------------
// Invariants (validated R5-R8, bit-level): after a crossing, xs is the exact
// boundary float c'*2^-5; direction never flips; per-(cell,dir) t_hit /
// a*t_hit constants; crossing count via search over the cumsum S (proven
// nondecreasing in f32: U_k == S_k by chain identity, th_k > 0).
// R9: once-per-point bounded-error substitutions with NO feedback path:
//   terminal expf -> v_exp_f32(ad*log2e)            (error enters output last)
//   step-0 logf/a -> v_log_f32(r)*fl64(ln2/a)       (<=2ulp of th, x12 max amp)
// Cumsum tables remain libm-exact (R3 lesson: per-step fast math re-poisons;
// once-per-point with bounded amplification does not).
// ---------------------------------------------------------------------------
__global__ __launch_bounds__(TPB) void cpab_flow(const float* __restrict__ x_in,
                                                 const float* __restrict__ theta,
                                                 float* __restrict__ out, int n) {
    __shared__ float sA[64];
    __shared__ float aS[NCC], bS[NCC], boaS[NCC], vLS[NCC], vRS[NCC], laS[NCC];
    __shared__ float thf[2][NCC], ljf[2][NCC];
    __shared__ float Sa[2 * NCC][33];   // cumsum S_k (nondecreasing), k=0..32
    __shared__ float La[2 * NCC][33];   // cumsum of fl32(a*th), k=0..32

    const int   tid = threadIdx.x;
    const float INF = __builtin_inff();

    if (tid < 64) {
        float acc = 0.0f;
#pragma unroll
        for (int j = 0; j < 33; ++j) acc = fmaf(dM.mt[j][tid], theta[j], acc);
        sA[tid] = acc;
    }
    __syncthreads();
    if (tid < NCC) {
        const float a   = sA[2 * tid];
        const float b   = sA[2 * tid + 1];
        const bool  big = fabsf(a) > EPSF;
        aS[tid]   = a;
        bS[tid]   = b;
        boaS[tid] = b / (big ? a : 1.0f);                       // IEEE divide
        laS[tid]  = (float)(0.6931471805599453094 / (double)(big ? a : 1.0f));
        vLS[tid]  = __fadd_rn(__fmul_rn(a, __fmul_rn((float)tid,       0.03125f)), b);
        vRS[tid]  = __fadd_rn(__fmul_rn(a, __fmul_rn((float)(tid + 1), 0.03125f)), b);
    }
    __syncthreads();
    if (tid < 2 * NCC) {
        // thf[d][c]: reference t_hit (libm-exact) for cell c entered moving
        // d (1=right, entry=c*h; 0=left, entry=(c+1)*h).
        const int   c     = tid & 31;
        const int   dd    = tid >> 5;
        const float a     = aS[c];
        const float b     = bS[c];
        const float entry = __fmul_rn((float)(c + (dd ? 0 : 1)), 0.03125f);
        const float v     = dd ? vLS[c] : vRS[c];
        const bool  dirA  = v > 0.0f;
        const bool  fin   = dirA ? (c < NCC - 1) : (c > 0);
        const float xb    = __fmul_rn((float)(c + (dirA ? 1 : 0)), 0.03125f);
        const float xcs   = fin ? xb : entry;
        const float vc    = fin ? (dirA ? vRS[c] : vLS[c]) : v;
        const bool  v0    = (v == 0.0f);
        const float r     = vc / (v0 ? 1.0f : v);               // IEEE divide
        const bool  big   = fabsf(a) > EPSF;
        const float a_s   = big ? a : 1.0f;
        const float th_a  = logf(fmaxf(r, EPSF)) / a_s;         // libm + divide
        const float bb    = (fabsf(b) > EPSF) ? b : 1.0f;
        const float th_b  = __fsub_rn(xcs, entry) / bb;
        float t_hit = big ? ((r > EPSF) ? th_a : INF) : th_b;
        const bool valid = fin && !v0 && (t_hit > 0.0f);
        t_hit = valid ? t_hit : INF;
        thf[dd][c] = t_hit;
        ljf[dd][c] = __fmul_rn(a, t_hit);
    }
    __syncthreads();
    if (tid < 2 * NCC) {
        // Per-(start cell c1, dir) cumsum. Guard entries (OOB / th>2) get
        // th=4 > 1 >= t0 so the search never selects past them.
        const int d  = tid >> 5;
        const int c1 = tid & 31;
        const int dh = d ? 1 : -1;
        float S = 0.0f, LJ = 0.0f;
        Sa[tid][0] = 0.0f;
        La[tid][0] = 0.0f;
#pragma unroll
        for (int k = 1; k <= 32; ++k) {
            const int cell = c1 + (k - 1) * dh;
            float th = 4.0f, lp = 0.0f;
            if (cell >= 0 && cell < NCC) {
                th = thf[d][cell];
                lp = ljf[d][cell];
                if (!(th <= 2.0f)) { th = 4.0f; lp = 0.0f; }
            }
            S  = __fadd_rn(S, th);
            LJ = __fadd_rn(LJ, lp);
            Sa[tid][k] = S;
            La[tid][k] = LJ;
        }
    }
    __syncthreads();

    const int ti   = blockIdx.x * blockDim.x + tid;
    const int base = ti << 2;
    if (base >= n) return;
    const bool full = (base + 3 < n);

    float4 xv;
    if (full) {
        xv = *reinterpret_cast<const float4*>(x_in + base);
    } else {
        xv.x = x_in[base];
        xv.y = (base + 1 < n) ? x_in[base + 1] : 0.0f;
        xv.z = (base + 2 < n) ? x_in[base + 2] : 0.0f;
        xv.w = 0.0f;
    }
    float4 zo, jo;

#pragma unroll
    for (int q = 0; q < 4; ++q) {
        const float x0 = (q == 0) ? xv.x : (q == 1) ? xv.y : (q == 2) ? xv.z : xv.w;
        int c0 = (int)floorf(__fmul_rn(x0, 32.0f));
        c0 = min(max(c0, 0), NCC - 1);

        // ---- step 0 from arbitrary x0 (v_log + tabulated ln2/a; r exact) ----
        const float a    = aS[c0];
        const float b    = bS[c0];
        const float v    = __fadd_rn(__fmul_rn(a, x0), b);
        const bool  dirA = v > 0.0f;
        const bool  fin  = dirA ? (c0 < NCC - 1) : (c0 > 0);
        const float xb   = __fmul_rn((float)(c0 + (dirA ? 1 : 0)), 0.03125f);
        const float xcs  = fin ? xb : x0;
        const float vc   = fin ? (dirA ? vRS[c0] : vLS[c0]) : v;
        const bool  v0   = (v == 0.0f);
        const float r    = vc / (v0 ? 1.0f : v);                // IEEE divide
        const bool  big  = fabsf(a) > EPSF;
        const float th_a = __builtin_amdgcn_logf(fmaxf(r, EPSF)) * laS[c0];
        float th_b = 0.0f;
        if (__any(!big)) {   // dead for gaussian A; exact when taken
            const float bb = (fabsf(b) > EPSF) ? b : 1.0f;
            th_b = __fsub_rn(xcs, x0) / bb;
        }
        float th = big ? ((r > EPSF) ? th_a : INF) : th_b;
        const bool valid = fin && !v0 && (th > 0.0f);
        th = valid ? th : INF;

        const bool  cross0 = th < 1.0f;
        const float t0     = __fsub_rn(1.0f, th);
        const float lj0    = __fmul_rn(a, th);
        const int   dh     = dirA ? 1 : -1;
        const int   c1     = c0 + dh;
        const int   c1c    = min(max(c1, 0), NCC - 1);
        const int   row    = (dirA ? NCC : 0) + c1c;

        // ---- crossing count: binary search over nondecreasing cumsum S ----
        int m = 0;
#pragma unroll
        for (int s = 32; s >= 1; s >>= 1) {
            const int   cand  = m + s;
            const int   candc = min(cand, 32);
            const float u     = Sa[row][candc];
            m = ((cand <= 32) && (t0 > u)) ? cand : m;
        }
        const float Sm = Sa[row][m];
        const float Lm = La[row][m];

        const float t  = cross0 ? __fsub_rn(t0, Sm) : 1.0f;
        const float lj = cross0 ? __fadd_rn(lj0, Lm) : 0.0f;
        int cf = cross0 ? (c1 + m * dh) : c0;
        cf = min(max(cf, 0), NCC - 1);
        const float xs = cross0 ? __fmul_rn((float)(cf + (dirA ? 0 : 1)), 0.03125f)
                                : x0;

        // ---- terminal: dt = t; exp via v_exp (last op, no feedback) ----
        const float af   = aS[cf];
        const float bf   = bS[cf];
        const bool  bigf = fabsf(af) > EPSF;
        const float boa  = boaS[cf];
        const float ad   = __fmul_rn(af, t);
        const float ea   = __builtin_amdgcn_exp2f(__fmul_rn(ad, 1.44269504088896340736f));
        const float psi  = bigf ? __fsub_rn(__fmul_rn(ea, __fadd_rn(xs, boa)), boa)
                                : __fadd_rn(xs, __fmul_rn(bf, t));
        const float ljo  = __fadd_rn(lj, ad);
        if (q == 0) { zo.x = psi; jo.x = ljo; }
        if (q == 1) { zo.y = psi; jo.y = ljo; }
        if (q == 2) { zo.z = psi; jo.z = ljo; }
        if (q == 3) { zo.w = psi; jo.w = ljo; }
    }

    if (full) {
        *reinterpret_cast<float4*>(out + base)     = zo;
        *reinterpret_cast<float4*>(out + n + base) = jo;
    } else {
        out[base] = zo.x;             out[n + base] = jo.x;
        if (base + 1 < n) { out[base + 1] = zo.y; out[n + base + 1] = jo.y; }
        if (base + 2 < n) { out[base + 2] = zo.z; out[n + base + 2] = jo.z; }
    }
}

extern "C" void kernel_launch(void* const* d_in, const int* in_sizes, int n_in,
                              void* d_out, int out_size, void* d_ws, size_t ws_size,
                              hipStream_t stream) {
    (void)d_ws; (void)ws_size; (void)n_in; (void)out_size;
    const float* x     = (const float*)d_in[0];
    const float* theta = (const float*)d_in[1];
    float*       out   = (float*)d_out;
    const int    n     = in_sizes[0];

    const int threads4 = (n + 3) >> 2;
    const int blocks   = (threads4 + TPB - 1) / TPB;
    cpab_flow<<<blocks, TPB, 0, stream>>>(x, theta, out, n);
}